// Round 9
// baseline (124.561 us; speedup 1.0000x reference)
//
#include <hip/hip_runtime.h>
#include <hip/hip_bf16.h>

#define B_    16
#define N_    4
#define COUT  256
#define CIN   256
#define H_    64
#define W_    64
#define K_TOT (CIN * 9)    // 2304, k = p*256 + cin (p-major)
#define HW    (H_ * W_)    // 4096
#define NKT   (K_TOT / 32) // 72 K-tiles of 32
#define PAD   66
#define PLANE (PAD * PAD)  // 4356 padded pixels per (b, cb4) plane

typedef __attribute__((ext_vector_type(8))) short short8;
typedef __attribute__((ext_vector_type(4))) float f32x4;
typedef unsigned short ushort_t;

static __device__ __forceinline__ ushort_t f2bf(float f) {
    __hip_bfloat16 h = __float2bfloat16(f);
    return *reinterpret_cast<ushort_t*>(&h);
}

typedef __attribute__((address_space(3))) unsigned int lds_u32;
typedef __attribute__((address_space(1))) const unsigned int glb_u32;
static __device__ __forceinline__ void gl_lds16(const ushort_t* g, ushort_t* l) {
    __builtin_amdgcn_global_load_lds((glb_u32*)g, (lds_u32*)l, 16, 0, 0);
}

#define BARRIER() asm volatile("s_barrier" ::: "memory")
#define VMCNTN(N) asm volatile("s_waitcnt vmcnt(" #N ")" ::: "memory")

// ---------------------------------------------------------------------------
// Kernel 1: 9x9 rotation matrices, scaled by alpha.  rm[b*N_+n][9][9] floats.
// ---------------------------------------------------------------------------
__global__ void rot_mats_kernel(const float* __restrict__ alphas,
                                const float* __restrict__ angles,
                                float* __restrict__ rm) {
    int i = threadIdx.x;
    if (i >= B_ * N_) return;
    float th = angles[i], al = alphas[i];
    float xc = cosf(th), ys = sinf(th);
    float a = xc - ys, b = xc * ys, c = xc + ys;
    float r[81];
#pragma unroll
    for (int j = 0; j < 81; ++j) r[j] = 0.f;
    if (th >= 0.f) {
        r[0] = a;          r[1] = 1.f - a;
        r[10] = xc - b;    r[11] = b;        r[13] = 1.f - c + b; r[14] = ys - b;
        r[20] = a;         r[23] = 1.f - a;
        r[27] = b;         r[28] = ys - b;   r[30] = xc - b;      r[31] = 1.f - c + b;
        r[40] = 1.f;
        r[49] = 1.f - c + b; r[50] = xc - b; r[52] = ys - b;      r[53] = b;
        r[57] = 1.f - a;   r[60] = a;
        r[66] = ys - b;    r[67] = 1.f - c + b; r[69] = b;        r[70] = xc - b;
        r[79] = 1.f - a;   r[80] = a;
    } else {
        r[0] = c;          r[3] = 1.f - c;
        r[9] = -b;         r[10] = xc + b;   r[12] = b - ys;      r[13] = 1.f - a - b;
        r[19] = 1.f - c;   r[20] = c;
        r[30] = xc + b;    r[31] = 1.f - a - b; r[33] = -b;       r[34] = b - ys;
        r[40] = 1.f;
        r[46] = b - ys;    r[47] = -b;       r[49] = 1.f - a - b; r[50] = xc + b;
        r[60] = c;         r[61] = 1.f - c;
        r[67] = 1.f - a - b; r[68] = b - ys; r[70] = xc + b;      r[71] = -b;
        r[77] = 1.f - c;   r[80] = c;
    }
#pragma unroll
    for (int j = 0; j < 81; ++j) rm[i * 81 + j] = r[j] * al;
}

// ---------------------------------------------------------------------------
// Kernel 2: rw[b][cout][p*256 + cin] (bf16, p-major K layout)
// ---------------------------------------------------------------------------
__global__ __launch_bounds__(256)
void build_rw_kernel(const float* __restrict__ weight,
                     const float* __restrict__ rm,
                     ushort_t* __restrict__ rw) {
    __shared__ float rms[N_ * 81];        // 324 floats
    int tid = threadIdx.x;
    int b = blockIdx.y;
    for (int j = tid; j < N_ * 81; j += 256)
        rms[j] = rm[b * N_ * 81 + j];
    __syncthreads();

    int idx = blockIdx.x * 256 + tid;     // cout*256 + cin
    int cout = idx >> 8, cin = idx & 255;

    float wv[N_][9];
#pragma unroll
    for (int n = 0; n < N_; ++n)
#pragma unroll
        for (int q = 0; q < 9; ++q)
            wv[n][q] = weight[(size_t)(n * (COUT * CIN) + idx) * 9 + q];

    ushort_t* dst = rw + (size_t)(b * COUT + cout) * K_TOT + cin;
#pragma unroll
    for (int p = 0; p < 9; ++p) {
        float s = 0.f;
#pragma unroll
        for (int n = 0; n < N_; ++n)
#pragma unroll
            for (int q = 0; q < 9; ++q)
                s += rms[n * 81 + p * 9 + q] * wv[n][q];
        dst[p * 256] = f2bf(s);
    }
}

// ---------------------------------------------------------------------------
// Kernel 2a: zero the halo ring of each padded plane (260 px x 64 cin).
// grid: 64 planes (b*4 + cb4).
// ---------------------------------------------------------------------------
__global__ __launch_bounds__(256)
void halo_zero_kernel(ushort_t* __restrict__ xt) {
    ushort_t* base = xt + (size_t)blockIdx.x * PLANE * 64;
    int t = threadIdx.x;
    for (int i = t; i < 260; i += 256) {
        int py, px;
        if (i < 66)       { py = 0;  px = i; }
        else if (i < 132) { py = 65; px = i - 66; }
        else if (i < 196) { py = i - 132 + 1; px = 0; }
        else              { py = i - 196 + 1; px = 65; }
        ushort_t* d = base + (size_t)(py * PAD + px) * 64;
        int4 z = {0, 0, 0, 0};
#pragma unroll
        for (int q = 0; q < 8; ++q) *(int4*)(d + q * 8) = z;
    }
}

// ---------------------------------------------------------------------------
// Kernel 2b: interior repack: x fp32 [b][c][64][64] -> xt bf16
//   [b][cb4(4)][y+1][x+1][64cin].  grid (64 rows, 8 cb32, B_), 256 thr.
// ---------------------------------------------------------------------------
__global__ __launch_bounds__(256)
void nhwc_kernel(const float* __restrict__ x, ushort_t* __restrict__ xt) {
    int y    = blockIdx.x;
    int cb32 = blockIdx.y;
    int b    = blockIdx.z;
    __shared__ ushort_t tileT[64][40];    // [px][ci(32)], 80B rows
    int t = threadIdx.x;

    int ci = t & 31, seg = t >> 5;        // 8 segs x 8 px
    const float* src = x + ((size_t)(b * CIN + cb32 * 32 + ci) * HW + y * 64 + seg * 8);
    float4 f0 = ((const float4*)src)[0];
    float4 f1 = ((const float4*)src)[1];
#pragma unroll
    for (int q = 0; q < 4; ++q) tileT[seg * 8 + q][ci]     = f2bf(((float*)&f0)[q]);
#pragma unroll
    for (int q = 0; q < 4; ++q) tileT[seg * 8 + 4 + q][ci] = f2bf(((float*)&f1)[q]);
    __syncthreads();

    int px = t >> 2, cseg = t & 3;        // 64 px x 4 x 16B
    ushort_t* dst = xt + ((size_t)(b * 4 + (cb32 >> 1)) * PLANE + (y + 1) * PAD + px + 1) * 64
                       + (cb32 & 1) * 32 + cseg * 8;
    *(int4*)dst = *(const int4*)&tileT[px][cseg * 8];
}

// ---------------------------------------------------------------------------
// Kernel 3: 256x256 implicit-GEMM conv, BK=32, 4-deep LDS pipeline with
// counted vmcnt (T3+T4), swizzle f(r)=(r&3)^((r>>2)&3) both sides (T2),
// setprio around MFMA (T5), bijective XCD swizzle (T1).
// 512 thr = 8 waves (2M x 4N), wave tile 128x64, acc[8][4].
// Per K-tile: 2 phases x 16 MFMA; stage tile kt+3 (A ph1, B ph2);
// vmcnt(8) at tile end -> issue-to-wait distance = 4 phases (~HBM latency).
// ---------------------------------------------------------------------------
__global__ __launch_bounds__(512, 1)
void conv_kernel(const ushort_t* __restrict__ xt,
                 const ushort_t* __restrict__ rw,
                 float* __restrict__ out) {
    int bid0 = blockIdx.x;
    int bid = (bid0 & 7) * 32 + (bid0 >> 3);   // 256 = 8*32: bijective
    int b    = bid >> 4;
    int tile = bid & 15;        // pixel tile: 4 image rows
    int y0 = tile * 4;
    int tid = threadIdx.x;
    int lane = tid & 63, wid = tid >> 6;
    int wm = wid >> 2, wn = wid & 3;
    int rA = lane & 15, kseg = lane >> 4;

    __shared__ __align__(16) ushort_t As[4][256][32];   // 64 KB
    __shared__ __align__(16) ushort_t Bs[4][256][32];   // 64 KB
    ushort_t* AsB = &As[0][0][0];
    ushort_t* BsB = &Bs[0][0][0];

    f32x4 acc[8][4] = {};

    const ushort_t* rwb  = rw + (size_t)b * COUT * K_TOT;
    const ushort_t* xtb2 = xt + (size_t)b * 4 * PLANE * 64 + (size_t)y0 * PAD * 64;

    // ---- staging geometry: unit u in {tid, 512+tid}; r=u>>2, sd=u&3 ----
    const int r0 = tid >> 2;                       // 0..127 (unit1: +128)
    const int sd = tid & 3;
    const int fs = (r0 & 3) ^ ((r0 >> 2) & 3);     // same for r0 and r0+128
    const int sg = (sd ^ fs) * 8;                  // source seg (elements)
    // A source row offsets (add k-offset per tile):
    const int a0 = r0 * K_TOT + sg;
    const int a1 = (r0 + 128) * K_TOT + sg;
    // B pixel offsets: r -> (prow = r>>6, pcol = r&63)
    const int pb0 = ((r0 >> 6) * PAD + (r0 & 63)) * 64 + sg;
    const int pb1 = pb0 + 2 * PAD * 64;            // prow+2 for r0+128
    // LDS dest (linear): unit u -> u*8 ushorts
    const int dd0 = tid * 8;
    const int dd1 = 4096 + tid * 8;
    // read-side swizzled column (lane-constant)
    const int fread = (rA & 3) ^ ((rA >> 2) & 3);
    const int cread = (kseg ^ fread) * 8;

#define STAGE_A(KTN)                                                           \
    {                                                                          \
        int p_ = (KTN) >> 3, c32_ = (KTN) & 7;                                 \
        int ako = p_ * 256 + c32_ * 32;                                        \
        ushort_t* db = AsB + ((KTN) & 3) * 8192;                               \
        gl_lds16(rwb + a0 + ako, db + dd0);                                    \
        gl_lds16(rwb + a1 + ako, db + dd1);                                    \
    }

#define STAGE_B(KTN)                                                           \
    {                                                                          \
        int p_ = (KTN) >> 3, cb4_ = ((KTN) & 7) >> 1, h_ = (KTN) & 1;          \
        int ph_ = p_ / 3, pw_ = p_ - 3 * ph_;                                  \
        const ushort_t* sb = xtb2 + (size_t)(cb4_ * PLANE + ph_ * PAD + pw_) * 64 \
                             + h_ * 32;                                        \
        ushort_t* db = BsB + ((KTN) & 3) * 8192;                               \
        gl_lds16(sb + pb0, db + dd0);                                          \
        gl_lds16(sb + pb1, db + dd1);                                          \
    }

#define READ_AF(Q, MH2)                                                        \
    _Pragma("unroll")                                                          \
    for (int mi = 0; mi < 4; ++mi) {                                           \
        int row = wm * 128 + (MH2) * 64 + mi * 16 + rA;                        \
        af[mi] = *(const short8*)(AsB + (Q) * 8192 + row * 32 + cread);        \
    }

#define READ_BF(Q)                                                             \
    _Pragma("unroll")                                                          \
    for (int ni = 0; ni < 4; ++ni) {                                           \
        int row = wn * 64 + ni * 16 + rA;                                      \
        bf[ni] = *(const short8*)(BsB + (Q) * 8192 + row * 32 + cread);        \
    }

#define DO_MFMA(MH2)                                                           \
    __builtin_amdgcn_s_setprio(1);                                             \
    _Pragma("unroll")                                                          \
    for (int mi = 0; mi < 4; ++mi)                                             \
        _Pragma("unroll")                                                      \
        for (int ni = 0; ni < 4; ++ni)                                         \
            acc[(MH2) * 4 + mi][ni] = __builtin_amdgcn_mfma_f32_16x16x32_bf16( \
                af[mi], bf[ni], acc[(MH2) * 4 + mi][ni], 0, 0, 0);             \
    __builtin_amdgcn_s_setprio(0);

    // ---- prologue: stage tiles 0,1,2 into buffers 0,1,2 ----
    STAGE_A(0); STAGE_B(0);
    STAGE_A(1); STAGE_B(1);
    STAGE_A(2); STAGE_B(2);
    VMCNTN(8);               // tile 0 landed (1,2 still in flight)
    BARRIER();

    short8 af[4], bf[4];
    for (int kt = 0; kt < NKT; ++kt) {
        int q = kt & 3;
        bool more = (kt + 3 < NKT);
        // ---- phase 1: m-half 0; stage A of kt+3 ----
        READ_AF(q, 0);
        READ_BF(q);
        if (more) STAGE_A(kt + 3);
        BARRIER();
        DO_MFMA(0);
        BARRIER();
        // ---- phase 2: m-half 1 (bf reused); stage B of kt+3 ----
        READ_AF(q, 1);
        if (more) STAGE_B(kt + 3);
        BARRIER();
        DO_MFMA(1);
        // counted drain: ensure tile kt+1 landed, keep kt+2/kt+3 in flight
        if (kt < NKT - 3)       { VMCNTN(8); }
        else if (kt == NKT - 3) { VMCNTN(4); }
        else if (kt == NKT - 2) { VMCNTN(0); }
        BARRIER();
    }
#undef STAGE_A
#undef STAGE_B
#undef READ_AF
#undef READ_BF
#undef DO_MFMA

    // ---- epilogue: D[row=(lane>>4)*4+rr][col=lane&15] ----
    int row0 = (lane >> 4) * 4;
    int col  = lane & 15;
    float* outb = out + (size_t)b * COUT * HW + tile * 256;
#pragma unroll
    for (int am = 0; am < 8; ++am)
#pragma unroll
        for (int an = 0; an < 4; ++an)
#pragma unroll
            for (int rr = 0; rr < 4; ++rr) {
                int m = wm * 128 + am * 16 + row0 + rr;
                int n = wn * 64 + an * 16 + col;
                outb[(size_t)m * HW + n] = acc[am][an][rr];
            }
}

// ---------------------------------------------------------------------------
extern "C" void kernel_launch(void* const* d_in, const int* in_sizes, int n_in,
                              void* d_out, int out_size, void* d_ws, size_t ws_size,
                              hipStream_t stream) {
    const float* x      = (const float*)d_in[0];
    const float* alphas = (const float*)d_in[1];
    const float* angles = (const float*)d_in[2];
    const float* weight = (const float*)d_in[3];
    float* out = (float*)d_out;

    // ws: rw 18.87 MB | xt 35.68 MB | rm 20.7 KB
    ushort_t* rw = (ushort_t*)d_ws;
    ushort_t* xt = (ushort_t*)((char*)d_ws + (size_t)B_ * COUT * K_TOT * 2);
    float*    rm = (float*)((char*)d_ws + (size_t)B_ * COUT * K_TOT * 2
                                        + (size_t)64 * PLANE * 64 * 2);

    rot_mats_kernel<<<1, 64, 0, stream>>>(alphas, angles, rm);
    build_rw_kernel<<<dim3(COUT * CIN / 256, B_), 256, 0, stream>>>(weight, rm, rw);
    halo_zero_kernel<<<64, 256, 0, stream>>>(xt);
    nhwc_kernel<<<dim3(64, 8, B_), 256, 0, stream>>>(x, xt);
    conv_kernel<<<256, 512, 0, stream>>>(xt, rw, out);
}